// Round 4
// baseline (281.375 us; speedup 1.0000x reference)
//
#include <hip/hip_runtime.h>
#include <stdint.h>

#define HEADS 8
#define DM 512
#define TT 12
#define WIN 3
#define NN 325
#define BB 4
#define HD 64
#define MROWS (BB*TT*NN)                  // 15600 rows for QKV gemm
#define VTS 352                           // padded VT row stride; cols 325..351 zeroed
#define QTN 11                            // q-tiles of 32 rows (11*32=352 >= 325)
static const size_t QKV_ELE = (size_t)MROWS * DM;  // 7,987,200 elems per q/k/v tensor

typedef unsigned short u16;
typedef __attribute__((ext_vector_type(8))) short bf16x8;
typedef __attribute__((ext_vector_type(4))) float f32x4;

#define MFMA(a,b,c) __builtin_amdgcn_mfma_f32_16x16x32_bf16(a, b, c, 0, 0, 0)

static __device__ __forceinline__ float ex2(float x) {
  float r; asm("v_exp_f32 %0, %1" : "=v"(r) : "v"(x)); return r;
}

static __device__ __forceinline__ u16 f2bf(float f) {
  uint32_t u = __float_as_uint(f);
  u += 0x7fff + ((u >> 16) & 1);   // RNE
  return (u16)(u >> 16);
}
// pack two f32 -> one u32 of 2 bf16 (truncating), lo in low half
static __device__ __forceinline__ uint32_t pk2(float hi, float lo) {
  return __builtin_amdgcn_perm(__float_as_uint(hi), __float_as_uint(lo), 0x07060302);
}
static __device__ __forceinline__ float bf2f(u16 h) {
  return __uint_as_float((uint32_t)h << 16);
}

// ---------------- pack W (RNE) + bias concat ----------------
__global__ void pack_w(const float* __restrict__ Wq, const float* __restrict__ Wk,
                       const float* __restrict__ Wv, const float* __restrict__ bq,
                       const float* __restrict__ bk, const float* __restrict__ bv,
                       u16* __restrict__ Wb, float* __restrict__ biasc) {
  int i = blockIdx.x * blockDim.x + threadIdx.x;
  const int n4 = (3 * 512 * 512) / 4;   // 196608
  if (i < n4) {
    int j = i << 2;
    int which = j >> 18;                 // 512*512 = 2^18
    int off4 = i & ((512 * 512 / 4) - 1);
    const float* src = which == 0 ? Wq : (which == 1 ? Wk : Wv);
    float4 v = ((const float4*)src)[off4];
    uint32_t a0 = (uint32_t)f2bf(v.x) | ((uint32_t)f2bf(v.y) << 16);
    uint32_t a1 = (uint32_t)f2bf(v.z) | ((uint32_t)f2bf(v.w) << 16);
    ((uint2*)Wb)[i] = make_uint2(a0, a1);
  }
  if (i < 1536 / 4) {
    int j = i << 2;
    int which = j >> 9;
    int off4 = i & 127;
    const float* src = which == 0 ? bq : (which == 1 ? bk : bv);
    ((float4*)biasc)[i] = ((const float4*)src)[off4];
  }
}

// ---------------- fused QKV projection GEMM (f32 x converted inline) ----------------
__global__ __launch_bounds__(256) void proj_gemm(
    const float* __restrict__ x,    // [M][512] f32
    const u16* __restrict__ W,      // [1536][512] bf16
    const float* __restrict__ bias, // [1536]
    u16* __restrict__ qkv)          // 3 x [B][T][H][N][64] bf16
{
  __shared__ u16 sA[128 * 32];
  __shared__ u16 sB[128 * 32];
  const int m0 = blockIdx.x * 128;
  const int n0 = blockIdx.y * 128;
  const int tid = threadIdx.x;
  const int lane = tid & 63;
  const int wid = tid >> 6;
  const int wr = wid >> 1, wc = wid & 1;

  f32x4 acc[4][4] = {};

  const int srow = tid >> 2;
  const int scol = (tid & 3) * 8;

  for (int k0 = 0; k0 < 512; k0 += 32) {
    __syncthreads();
#pragma unroll
    for (int i = 0; i < 2; ++i) {
      int row = i * 64 + srow;
      int gm = m0 + row; if (gm >= MROWS) gm = MROWS - 1;
      const float* xa = x + (size_t)gm * 512 + k0 + scol;
      float4 f0 = *(const float4*)xa;
      float4 f1 = *(const float4*)(xa + 4);
      uint4 u;
      u.x = pk2(f0.y, f0.x);
      u.y = pk2(f0.w, f0.z);
      u.z = pk2(f1.y, f1.x);
      u.w = pk2(f1.w, f1.z);
      *(uint4*)&sA[row * 32 + scol] = u;
      *(bf16x8*)&sB[row * 32 + scol] = *(const bf16x8*)&W[(size_t)(n0 + row) * 512 + k0 + scol];
    }
    __syncthreads();
    bf16x8 af[4], bfr[4];
#pragma unroll
    for (int mi = 0; mi < 4; ++mi)
      af[mi] = *(const bf16x8*)&sA[(wr * 64 + mi * 16 + (lane & 15)) * 32 + (lane >> 4) * 8];
#pragma unroll
    for (int ni = 0; ni < 4; ++ni)
      bfr[ni] = *(const bf16x8*)&sB[(wc * 64 + ni * 16 + (lane & 15)) * 32 + (lane >> 4) * 8];
#pragma unroll
    for (int mi = 0; mi < 4; ++mi)
#pragma unroll
      for (int ni = 0; ni < 4; ++ni)
        acc[mi][ni] = MFMA(af[mi], bfr[ni], acc[mi][ni]);
  }

  const int lr = (lane >> 4) * 4;
  const int lc = lane & 15;
#pragma unroll
  for (int mi = 0; mi < 4; ++mi) {
#pragma unroll
    for (int j = 0; j < 4; ++j) {
      int gm = m0 + wr * 64 + mi * 16 + lr + j;
      if (gm < MROWS) {
        int b = gm / (TT * NN);
        int rem = gm - b * (TT * NN);
        int t = rem / NN;
        int n = rem - t * NN;
#pragma unroll
        for (int ni = 0; ni < 4; ++ni) {
          int e = n0 + wc * 64 + ni * 16 + lc;
          float val = acc[mi][ni][j] + bias[e];
          int which = e >> 9;
          int h = (e >> 6) & 7;
          int d = e & 63;
          qkv[(size_t)which * QKV_ELE + ((((size_t)(b * TT + t) * HEADS + h) * NN + n) << 6) + d] = f2bf(val);
        }
      }
    }
  }
}

// ---------------- V transpose: [slab][325][64] -> [slab][64][VTS], zero pad cols ----------------
__global__ __launch_bounds__(256) void vt_pack(const u16* __restrict__ v, u16* __restrict__ vt) {
  __shared__ u16 sv[325 * 66];
  int slab = blockIdx.x;            // (b*T + t)*H + h
  const u16* src = v + (size_t)slab * 325 * 64;
  u16* dst = vt + (size_t)slab * 64 * VTS;
  int tid = threadIdx.x;
  for (int i = tid; i < 325 * 16; i += 256) {
    int n = i >> 4, dd = (i & 15) * 4;
    uint2 w = *(const uint2*)(src + n * 64 + dd);
    *(uint*)(sv + n * 66 + dd) = w.x;
    *(uint*)(sv + n * 66 + dd + 2) = w.y;
  }
  __syncthreads();
  for (int d = 0; d < 64; ++d)
    for (int n = tid; n < VTS; n += 256)
      dst[d * VTS + n] = (n < NN) ? sv[n * 66 + d] : (u16)0;
}

// ---------------- MFMA attention, v4: barrier-free, 32 q-rows/wave ----------------
// Grid grouped by (b, t_adj) so the 66 blocks sharing one adj slab are consecutive,
// + m204 XCD swizzle so they land on one XCD's L2. adj read per-lane from global
// (L1/L2-cached, 4 head-waves/block share lines). No LDS, no barriers.
// Swapped QK^T (S^T = mfma(K_perm, Q)) so P lands in the PV A-frag with zero shuffles.
// Fixed softmax shift (m=8): p = exp(z-8), exp via raw v_exp_f32.
__global__ __launch_bounds__(256, 3) void attn(
    const u16* __restrict__ qkv,    // q at 0, k at QKV_ELE
    const u16* __restrict__ vt,     // [384][64][VTS]
    const float* __restrict__ adj,
    u16* __restrict__ hcat)         // [B][36][N][512] bf16
{
  const int tid = threadIdx.x;
  const int wid = tid >> 6;
  const int lane = tid & 63;
  const int qi = lane & 15;
  const int g = lane >> 4;

  // XCD swizzle: nwg = 3168 = 8 * 396
  int ord = (blockIdx.x & 7) * 396 + (blockIdx.x >> 3);
  int slab = ord / 66;               // 0..47 = b*12 + ta
  int inner = ord - slab * 66;
  int b = slab / 12;
  int ta = slab - b * 12;            // t_adj
  int ti = inner / 22;
  int r2 = inner - ti * 22;
  int qt = r2 >> 1;
  int hg = r2 & 1;

  int tadd = ti == 0 ? 3 : (ti == 1 ? 2 : 1);           // t = ta + tadd (mod 12)
  int ckv  = ti == 0 ? 9 : (ti == 1 ? 7 : 6);           // t_kv = t + ckv (mod 12)
  float qsc = ti == 0 ? 0.125f : (ti == 1 ? 0.015625f : 0.001953125f);
  int t = ta + tadd; if (t >= 12) t -= 12;
  int t_kv = t + ckv; if (t_kv >= 12) t_kv -= 12;
  int h = hg * 4 + wid;
  int q0 = qt * 32;

  const u16* qbase  = qkv + ((((size_t)(b * TT + t) * HEADS + h) * NN) << 6);
  const u16* kbase  = qkv + QKV_ELE + ((((size_t)(b * TT + t_kv) * HEADS + h) * NN) << 6);
  const u16* vtbase = vt + (size_t)((b * TT + t_kv) * HEADS + h) * 64 * VTS;
  const float* adjbase = adj + (size_t)(b * TT + ta) * NN * NN;

  // rows for the two 16-row subtiles
  int qr0 = q0 + qi;      if (qr0 > NN - 1) qr0 = NN - 1;
  int qr1 = q0 + 16 + qi; if (qr1 > NN - 1) qr1 = NN - 1;

  // Q fragments (B-operand): Q[row][g*8+e | 32+g*8+e]
  bf16x8 qf[2][2];
  {
    const u16* qp0 = qbase + (size_t)qr0 * 64 + g * 8;
    const u16* qp1 = qbase + (size_t)qr1 * 64 + g * 8;
    qf[0][0] = *(const bf16x8*)qp0;  qf[0][1] = *(const bf16x8*)(qp0 + 32);
    qf[1][0] = *(const bf16x8*)qp1;  qf[1][1] = *(const bf16x8*)(qp1 + 32);
  }

  const float* arow0 = adjbase + (size_t)qr0 * NN;
  const float* arow1 = adjbase + (size_t)qr1 * NN;
  const float* ag0 = arow0 + g * 8;
  const float* ag1 = arow1 + g * 8;

  const int rmap = ((qi >> 2) << 3) + (qi & 3);   // K row permutation
  const u16* kb2 = kbase + (size_t)rmap * 64 + g * 8;
  const u16* vb2 = vtbase + (size_t)qi * VTS + g * 8;

  const f32x4 z4 = {0.f, 0.f, 0.f, 0.f};
  const float LG = 1.44269504f;
  const float C8 = -11.5415603f;     // -8*log2(e)

  f32x4 acc[2][4] = {};
  float lsum[2] = {0.f, 0.f};

  // tile-0 prefetch
  bf16x8 kc0 = *(const bf16x8*)(kb2);
  bf16x8 kc1 = *(const bf16x8*)(kb2 + 32);
  bf16x8 kc2 = *(const bf16x8*)(kb2 + 256);
  bf16x8 kc3 = *(const bf16x8*)(kb2 + 256 + 32);
  bf16x8 vc0 = *(const bf16x8*)(vb2);
  bf16x8 vc1 = *(const bf16x8*)(vb2 + 16 * VTS);
  bf16x8 vc2 = *(const bf16x8*)(vb2 + 32 * VTS);
  bf16x8 vc3 = *(const bf16x8*)(vb2 + 48 * VTS);

  for (int kt = 0; kt < 10; ++kt) {
    const int K0 = kt * 32;
    // next-tile K/VT prefetch
    bf16x8 kn0, kn1, kn2, kn3, vn0, vn1, vn2, vn3;
    if (kt < 9) {
      const u16* kp = kb2 + (K0 + 32) * 64;
      kn0 = *(const bf16x8*)(kp);
      kn1 = *(const bf16x8*)(kp + 32);
      kn2 = *(const bf16x8*)(kp + 256);
      kn3 = *(const bf16x8*)(kp + 256 + 32);
      const u16* vp = vb2 + (K0 + 32);
      vn0 = *(const bf16x8*)(vp);
      vn1 = *(const bf16x8*)(vp + 16 * VTS);
      vn2 = *(const bf16x8*)(vp + 32 * VTS);
      vn3 = *(const bf16x8*)(vp + 48 * VTS);
    }
    // adj for this tile (per-lane, through L1/L2)
    float4 fa0 = *(const float4*)(ag0 + K0);
    float4 fb0 = *(const float4*)(ag0 + K0 + 4);
    float4 fa1 = *(const float4*)(ag1 + K0);
    float4 fb1 = *(const float4*)(ag1 + K0 + 4);

    // QK^T for both subtiles (8 MFMA)
    f32x4 s00 = MFMA(kc0, qf[0][0], z4);  s00 = MFMA(kc1, qf[0][1], s00);
    f32x4 s01 = MFMA(kc2, qf[0][0], z4);  s01 = MFMA(kc3, qf[0][1], s01);
    f32x4 s10 = MFMA(kc0, qf[1][0], z4);  s10 = MFMA(kc1, qf[1][1], s10);
    f32x4 s11 = MFMA(kc2, qf[1][0], z4);  s11 = MFMA(kc3, qf[1][1], s11);

    // subtile 0
    {
      float p[8];
      float av;
      av = fa0.x; p[0] = ex2(__builtin_fmaf(__builtin_fmaf(s00[0], av * qsc, av), LG, C8));
      av = fa0.y; p[1] = ex2(__builtin_fmaf(__builtin_fmaf(s00[1], av * qsc, av), LG, C8));
      av = fa0.z; p[2] = ex2(__builtin_fmaf(__builtin_fmaf(s00[2], av * qsc, av), LG, C8));
      av = fa0.w; p[3] = ex2(__builtin_fmaf(__builtin_fmaf(s00[3], av * qsc, av), LG, C8));
      av = fb0.x; p[4] = ex2(__builtin_fmaf(__builtin_fmaf(s01[0], av * qsc, av), LG, C8));
      av = fb0.y; p[5] = ex2(__builtin_fmaf(__builtin_fmaf(s01[1], av * qsc, av), LG, C8));
      av = fb0.z; p[6] = ex2(__builtin_fmaf(__builtin_fmaf(s01[2], av * qsc, av), LG, C8));
      av = fb0.w; p[7] = ex2(__builtin_fmaf(__builtin_fmaf(s01[3], av * qsc, av), LG, C8));
      lsum[0] += ((p[0] + p[1]) + (p[2] + p[3])) + ((p[4] + p[5]) + (p[6] + p[7]));
      union { uint32_t u[4]; bf16x8 v; } pu;
      pu.u[0] = pk2(p[1], p[0]);
      pu.u[1] = pk2(p[3], p[2]);
      pu.u[2] = pk2(p[5], p[4]);
      pu.u[3] = pk2(p[7], p[6]);
      acc[0][0] = MFMA(pu.v, vc0, acc[0][0]);
      acc[0][1] = MFMA(pu.v, vc1, acc[0][1]);
      acc[0][2] = MFMA(pu.v, vc2, acc[0][2]);
      acc[0][3] = MFMA(pu.v, vc3, acc[0][3]);
    }
    // subtile 1
    {
      float p[8];
      float av;
      av = fa1.x; p[0] = ex2(__builtin_fmaf(__builtin_fmaf(s10[0], av * qsc, av), LG, C8));
      av = fa1.y; p[1] = ex2(__builtin_fmaf(__builtin_fmaf(s10[1], av * qsc, av), LG, C8));
      av = fa1.z; p[2] = ex2(__builtin_fmaf(__builtin_fmaf(s10[2], av * qsc, av), LG, C8));
      av = fa1.w; p[3] = ex2(__builtin_fmaf(__builtin_fmaf(s10[3], av * qsc, av), LG, C8));
      av = fb1.x; p[4] = ex2(__builtin_fmaf(__builtin_fmaf(s11[0], av * qsc, av), LG, C8));
      av = fb1.y; p[5] = ex2(__builtin_fmaf(__builtin_fmaf(s11[1], av * qsc, av), LG, C8));
      av = fb1.z; p[6] = ex2(__builtin_fmaf(__builtin_fmaf(s11[2], av * qsc, av), LG, C8));
      av = fb1.w; p[7] = ex2(__builtin_fmaf(__builtin_fmaf(s11[3], av * qsc, av), LG, C8));
      lsum[1] += ((p[0] + p[1]) + (p[2] + p[3])) + ((p[4] + p[5]) + (p[6] + p[7]));
      union { uint32_t u[4]; bf16x8 v; } pu;
      pu.u[0] = pk2(p[1], p[0]);
      pu.u[1] = pk2(p[3], p[2]);
      pu.u[2] = pk2(p[5], p[4]);
      pu.u[3] = pk2(p[7], p[6]);
      acc[1][0] = MFMA(pu.v, vc0, acc[1][0]);
      acc[1][1] = MFMA(pu.v, vc1, acc[1][1]);
      acc[1][2] = MFMA(pu.v, vc2, acc[1][2]);
      acc[1][3] = MFMA(pu.v, vc3, acc[1][3]);
    }
    kc0 = kn0; kc1 = kn1; kc2 = kn2; kc3 = kn3;
    vc0 = vn0; vc1 = vn1; vc2 = vn2; vc3 = vn3;
  }

  // ---- tail tile: keys 320..324 ----
  {
    const int T0 = 320;
    int r0 = T0 + rmap;     if (r0 > NN - 1) r0 = NN - 1;
    int r1 = T0 + rmap + 4; if (r1 > NN - 1) r1 = NN - 1;
    const u16* kp0 = kbase + (size_t)r0 * 64 + g * 8;
    const u16* kp1 = kbase + (size_t)r1 * 64 + g * 8;
    kc0 = *(const bf16x8*)kp0;  kc1 = *(const bf16x8*)(kp0 + 32);
    kc2 = *(const bf16x8*)kp1;  kc3 = *(const bf16x8*)(kp1 + 32);
    const u16* vp = vb2 + T0;                    // cols >= 325 are zero-padded
    vc0 = *(const bf16x8*)(vp);
    vc1 = *(const bf16x8*)(vp + 16 * VTS);
    vc2 = *(const bf16x8*)(vp + 32 * VTS);
    vc3 = *(const bf16x8*)(vp + 48 * VTS);

    f32x4 s00 = MFMA(kc0, qf[0][0], z4);  s00 = MFMA(kc1, qf[0][1], s00);
    f32x4 s01 = MFMA(kc2, qf[0][0], z4);  s01 = MFMA(kc3, qf[0][1], s01);
    f32x4 s10 = MFMA(kc0, qf[1][0], z4);  s10 = MFMA(kc1, qf[1][1], s10);
    f32x4 s11 = MFMA(kc2, qf[1][0], z4);  s11 = MFMA(kc3, qf[1][1], s11);

#pragma unroll
    for (int s = 0; s < 2; ++s) {
      const float* arow = s == 0 ? arow0 : arow1;
      const f32x4& sv0 = s == 0 ? s00 : s10;
      const f32x4& sv1 = s == 0 ? s01 : s11;
      float p[8];
#pragma unroll
      for (int j = 0; j < 4; ++j) {
        int ko = g * 8 + j;
        float av = arow[T0 + (ko > 4 ? 4 : ko)];
        float pv = ex2(__builtin_fmaf(__builtin_fmaf(sv0[j], av * qsc, av), LG, C8));
        p[j] = (ko < 5) ? pv : 0.f;
      }
#pragma unroll
      for (int j = 0; j < 4; ++j) {
        int ko = g * 8 + 4 + j;
        float av = arow[T0 + (ko > 4 ? 4 : ko)];
        float pv = ex2(__builtin_fmaf(__builtin_fmaf(sv1[j], av * qsc, av), LG, C8));
        p[4 + j] = (ko < 5) ? pv : 0.f;
      }
      lsum[s] += ((p[0] + p[1]) + (p[2] + p[3])) + ((p[4] + p[5]) + (p[6] + p[7]));
      union { uint32_t u[4]; bf16x8 v; } pu;
      pu.u[0] = pk2(p[1], p[0]);
      pu.u[1] = pk2(p[3], p[2]);
      pu.u[2] = pk2(p[5], p[4]);
      pu.u[3] = pk2(p[7], p[6]);
      acc[s][0] = MFMA(pu.v, vc0, acc[s][0]);
      acc[s][1] = MFMA(pu.v, vc1, acc[s][1]);
      acc[s][2] = MFMA(pu.v, vc2, acc[s][2]);
      acc[s][3] = MFMA(pu.v, vc3, acc[s][3]);
    }
  }

  // ---- epilogue: normalize + store ----
  size_t hb = ((size_t)(b * 36 + ti * TT + t) * NN) << 9;
#pragma unroll
  for (int s = 0; s < 2; ++s) {
    float v = lsum[s];
    v += __shfl_xor(v, 16);
    v += __shfl_xor(v, 32);
    float linv = 1.0f / v;
#pragma unroll
    for (int j = 0; j < 4; ++j) {
      float li = __shfl(linv, g * 4 + j);
      int qrow = q0 + s * 16 + 4 * g + j;
      if (qrow < NN) {
        u16* op = hcat + hb + ((size_t)qrow << 9) + h * 64 + qi;
#pragma unroll
        for (int dt = 0; dt < 4; ++dt)
          op[dt * 16] = f2bf(acc[s][dt][j] * li);
      }
    }
  }
}

// ---------------- temporal mix + residual + LayerNorm ----------------
__global__ __launch_bounds__(256) void mix_ln(
    const u16* __restrict__ hcat,
    const float* __restrict__ Wd,   // [12][36]
    const float* __restrict__ bd,   // [12]
    const float* __restrict__ x,
    const float* __restrict__ gamma,
    const float* __restrict__ beta,
    float* __restrict__ out)
{
  __shared__ float sH[36 * 512];
  __shared__ float sWd[12 * 36];
  __shared__ float sred[8];
  int bn = blockIdx.x;
  int b = bn / NN, n = bn - b * NN;
  int tid = threadIdx.x;
  int lane = tid & 63, wid = tid >> 6;

  for (int i = tid; i < 12 * 36; i += 256) sWd[i] = Wd[i];
  for (int i = tid; i < 36 * 512; i += 256) {
    int w = i >> 9, d = i & 511;
    sH[i] = bf2f(hcat[(((size_t)(b * 36 + w) * NN + n) << 9) + d]);
  }
  __syncthreads();

  for (int t = 0; t < TT; ++t) {
    float a0 = 0.f, a1 = 0.f;
#pragma unroll
    for (int w = 0; w < 36; ++w) {
      float wv = sWd[t * 36 + w];
      a0 += sH[(w << 9) + tid] * wv;
      a1 += sH[(w << 9) + 256 + tid] * wv;
    }
    size_t xoff = ((size_t)(b * TT + t) * NN + n) << 9;
    float bdt = bd[t];
    float y0 = a0 + bdt + x[xoff + tid];
    float y1 = a1 + bdt + x[xoff + 256 + tid];
    float s = y0 + y1, ss = y0 * y0 + y1 * y1;
#pragma unroll
    for (int off = 32; off > 0; off >>= 1) {
      s += __shfl_down(s, off);
      ss += __shfl_down(ss, off);
    }
    if (lane == 0) { sred[wid * 2] = s; sred[wid * 2 + 1] = ss; }
    __syncthreads();
    float stot = sred[0] + sred[2] + sred[4] + sred[6];
    float sstot = sred[1] + sred[3] + sred[5] + sred[7];
    float mu = stot * (1.0f / 512.0f);
    float var = sstot * (1.0f / 512.0f) - mu * mu;
    float rstd = rsqrtf(var + 1e-5f);
    out[xoff + tid] = (y0 - mu) * rstd * gamma[tid] + beta[tid];
    out[xoff + 256 + tid] = (y1 - mu) * rstd * gamma[tid + 256] + beta[tid + 256];
    __syncthreads();
  }
}

extern "C" void kernel_launch(void* const* d_in, const int* in_sizes, int n_in,
                              void* d_out, int out_size, void* d_ws, size_t ws_size,
                              hipStream_t stream) {
  const float* x     = (const float*)d_in[0];
  const float* adj   = (const float*)d_in[1];
  // d_in[2] = s_adj: unused by the reference
  const float* Wq    = (const float*)d_in[3];
  const float* bq    = (const float*)d_in[4];
  const float* Wk    = (const float*)d_in[5];
  const float* bk    = (const float*)d_in[6];
  const float* Wv    = (const float*)d_in[7];
  const float* bv    = (const float*)d_in[8];
  const float* Wd    = (const float*)d_in[9];
  const float* bd    = (const float*)d_in[10];
  const float* gamma = (const float*)d_in[11];
  const float* beta  = (const float*)d_in[12];
  float* out = (float*)d_out;

  char* ws = (char*)d_ws;
  size_t off = 0;
  auto alloc = [&](size_t bytes) {
    void* p = ws + off;
    off += (bytes + 255) & ~(size_t)255;
    return p;
  };
  u16* Wb     = (u16*)alloc(1536 * 512 * 2);         // [Wq;Wk;Wv] bf16
  float* bias = (float*)alloc(1536 * 4);             // [bq;bk;bv]
  u16* qkv    = (u16*)alloc(3 * QKV_ELE * 2);        // q,k,v bf16 (B,T,H,N,64)
  u16* hcat   = (u16*)alloc(3 * QKV_ELE * 2);        // (B,36,N,512) bf16
  u16* vtb    = (u16*)alloc((size_t)BB * TT * HEADS * 64 * VTS * 2);  // V^T padded

  pack_w<<<dim3(768), dim3(256), 0, stream>>>(Wq, Wk, Wv, bq, bk, bv, Wb, bias);
  proj_gemm<<<dim3((MROWS + 127) / 128, 1536 / 128), dim3(256), 0, stream>>>(x, Wb, bias, qkv);
  vt_pack<<<dim3(BB * TT * HEADS), dim3(256), 0, stream>>>(qkv + 2 * QKV_ELE, vtb);
  attn<<<dim3(BB * TT * WIN * QTN * 2), dim3(256), 0, stream>>>(qkv, vtb, adj, hcat);
  mix_ln<<<dim3(BB * NN), dim3(256), 0, stream>>>(hcat, Wd, bd, x, gamma, beta, out);
}

// Round 5
// 266.893 us; speedup vs baseline: 1.0543x; 1.0543x over previous
//
#include <hip/hip_runtime.h>
#include <stdint.h>

#define HEADS 8
#define DM 512
#define TT 12
#define WIN 3
#define NN 325
#define BB 4
#define HD 64
#define MROWS (BB*TT*NN)                  // 15600 rows for QKV gemm
#define VTS 352                           // padded VT row stride; pad cols never contribute (p=0)
static const size_t QKV_ELE = (size_t)MROWS * DM;  // 7,987,200 elems per q/k tensor

typedef unsigned short u16;
typedef __attribute__((ext_vector_type(8))) short bf16x8;
typedef __attribute__((ext_vector_type(4))) float f32x4;

#define MFMA(a,b,c) __builtin_amdgcn_mfma_f32_16x16x32_bf16(a, b, c, 0, 0, 0)

static __device__ __forceinline__ float ex2(float x) {
  float r; asm("v_exp_f32 %0, %1" : "=v"(r) : "v"(x)); return r;
}

static __device__ __forceinline__ u16 f2bf(float f) {
  uint32_t u = __float_as_uint(f);
  u += 0x7fff + ((u >> 16) & 1);   // RNE
  return (u16)(u >> 16);
}
// pack two f32 -> one u32 of 2 bf16 (truncating), lo in low half
static __device__ __forceinline__ uint32_t pk2(float hi, float lo) {
  return __builtin_amdgcn_perm(__float_as_uint(hi), __float_as_uint(lo), 0x07060302);
}
static __device__ __forceinline__ float bf2f(u16 h) {
  return __uint_as_float((uint32_t)h << 16);
}

// ---------------- pack W (RNE) + bias concat ----------------
__global__ void pack_w(const float* __restrict__ Wq, const float* __restrict__ Wk,
                       const float* __restrict__ Wv, const float* __restrict__ bq,
                       const float* __restrict__ bk, const float* __restrict__ bv,
                       u16* __restrict__ Wb, float* __restrict__ biasc) {
  int i = blockIdx.x * blockDim.x + threadIdx.x;
  const int n4 = (3 * 512 * 512) / 4;   // 196608
  if (i < n4) {
    int j = i << 2;
    int which = j >> 18;                 // 512*512 = 2^18
    int off4 = i & ((512 * 512 / 4) - 1);
    const float* src = which == 0 ? Wq : (which == 1 ? Wk : Wv);
    float4 v = ((const float4*)src)[off4];
    uint32_t a0 = (uint32_t)f2bf(v.x) | ((uint32_t)f2bf(v.y) << 16);
    uint32_t a1 = (uint32_t)f2bf(v.z) | ((uint32_t)f2bf(v.w) << 16);
    ((uint2*)Wb)[i] = make_uint2(a0, a1);
  }
  if (i < 1536 / 4) {
    int j = i << 2;
    int which = j >> 9;
    int off4 = i & 127;
    const float* src = which == 0 ? bq : (which == 1 ? bk : bv);
    ((float4*)biasc)[i] = ((const float4*)src)[off4];
  }
}

// ---------------- fused QKV projection GEMM; V written directly transposed ----------------
__global__ __launch_bounds__(256) void proj_gemm(
    const float* __restrict__ x,    // [M][512] f32
    const u16* __restrict__ W,      // [1536][512] bf16
    const float* __restrict__ bias, // [1536]
    u16* __restrict__ qkv,          // 2 x [B][T][H][N][64] bf16 (q, k)
    u16* __restrict__ vt)           // [384][64][VTS] bf16 (V transposed)
{
  __shared__ u16 sA[128 * 32];
  __shared__ u16 sB[128 * 32];
  const int m0 = blockIdx.x * 128;
  const int n0 = blockIdx.y * 128;
  const int tid = threadIdx.x;
  const int lane = tid & 63;
  const int wid = tid >> 6;
  const int wr = wid >> 1, wc = wid & 1;

  f32x4 acc[4][4] = {};

  const int srow = tid >> 2;
  const int scol = (tid & 3) * 8;

  for (int k0 = 0; k0 < 512; k0 += 32) {
    __syncthreads();
#pragma unroll
    for (int i = 0; i < 2; ++i) {
      int row = i * 64 + srow;
      int gm = m0 + row; if (gm >= MROWS) gm = MROWS - 1;
      const float* xa = x + (size_t)gm * 512 + k0 + scol;
      float4 f0 = *(const float4*)xa;
      float4 f1 = *(const float4*)(xa + 4);
      uint4 u;
      u.x = pk2(f0.y, f0.x);
      u.y = pk2(f0.w, f0.z);
      u.z = pk2(f1.y, f1.x);
      u.w = pk2(f1.w, f1.z);
      *(uint4*)&sA[row * 32 + scol] = u;
      *(bf16x8*)&sB[row * 32 + scol] = *(const bf16x8*)&W[(size_t)(n0 + row) * 512 + k0 + scol];
    }
    __syncthreads();
    bf16x8 af[4], bfr[4];
#pragma unroll
    for (int mi = 0; mi < 4; ++mi)
      af[mi] = *(const bf16x8*)&sA[(wr * 64 + mi * 16 + (lane & 15)) * 32 + (lane >> 4) * 8];
#pragma unroll
    for (int ni = 0; ni < 4; ++ni)
      bfr[ni] = *(const bf16x8*)&sB[(wc * 64 + ni * 16 + (lane & 15)) * 32 + (lane >> 4) * 8];
#pragma unroll
    for (int mi = 0; mi < 4; ++mi)
#pragma unroll
      for (int ni = 0; ni < 4; ++ni)
        acc[mi][ni] = MFMA(af[mi], bfr[ni], acc[mi][ni]);
  }

  const int lr = (lane >> 4) * 4;
  const int lc = lane & 15;
#pragma unroll
  for (int mi = 0; mi < 4; ++mi) {
#pragma unroll
    for (int j = 0; j < 4; ++j) {
      int gm = m0 + wr * 64 + mi * 16 + lr + j;
      if (gm < MROWS) {
        int b = gm / (TT * NN);
        int rem = gm - b * (TT * NN);
        int t = rem / NN;
        int n = rem - t * NN;
#pragma unroll
        for (int ni = 0; ni < 4; ++ni) {
          int e = n0 + wc * 64 + ni * 16 + lc;
          float val = acc[mi][ni][j] + bias[e];
          int which = e >> 9;
          int h = (e >> 6) & 7;
          int d = e & 63;
          int slab = (b * TT + t) * HEADS + h;
          if (which < 2) {
            qkv[(size_t)which * QKV_ELE + (((size_t)slab * NN + n) << 6) + d] = f2bf(val);
          } else {
            vt[(size_t)slab * 64 * VTS + (size_t)d * VTS + n] = f2bf(val);
          }
        }
      }
    }
  }
}

// ---------------- MFMA attention, v5: 64 q-rows/wave, barrier-free ----------------
// Block = 4 waves = 4 heads (hg*4..hg*4+3) of one (b,t,ti,qt); NO LDS, NO barriers.
// Grid grouped by (b,t_adj) + m204-style XCD swizzle so the 36 blocks sharing one
// 422 KB adj slab land on one XCD's L2. adj read per-lane from global (L1-shared
// across the 4 head-waves). Swapped QK^T (S^T = mfma(K_perm, Q)) so P lands in the
// PV A-frag with zero shuffles. Fixed softmax shift (m=8): p = exp(z-8).
__global__ __launch_bounds__(256, 2) void attn(
    const u16* __restrict__ qkv,    // q at 0, k at QKV_ELE
    const u16* __restrict__ vt,     // [384][64][VTS]
    const float* __restrict__ adj,
    u16* __restrict__ hcat)         // [B][36][N][512] bf16
{
  const int tid = threadIdx.x;
  const int wid = tid >> 6;
  const int lane = tid & 63;
  const int qi = lane & 15;
  const int g = lane >> 4;

  // XCD swizzle: nwg = 1728 = 8 * 216
  int ord = (blockIdx.x & 7) * 216 + (blockIdx.x >> 3);
  int slab = ord / 36;               // 0..47 = b*12 + ta
  int inner = ord - slab * 36;
  int b = slab / 12;
  int ta = slab - b * 12;            // t_adj
  int ti = inner / 12;
  int r2 = inner - ti * 12;
  int qt = r2 >> 1;
  int hg = r2 & 1;

  int tadd = ti == 0 ? 3 : (ti == 1 ? 2 : 1);           // t = ta + tadd (mod 12)
  int ckv  = ti == 0 ? 9 : (ti == 1 ? 7 : 6);           // t_kv = t + ckv (mod 12)
  float qsc = ti == 0 ? 0.125f : (ti == 1 ? 0.015625f : 0.001953125f);
  int t = ta + tadd; if (t >= 12) t -= 12;
  int t_kv = t + ckv; if (t_kv >= 12) t_kv -= 12;
  int h = hg * 4 + wid;
  int q0 = qt * 64;

  const u16* qbase  = qkv + ((((size_t)(b * TT + t) * HEADS + h) * NN) << 6);
  const u16* kbase  = qkv + QKV_ELE + ((((size_t)(b * TT + t_kv) * HEADS + h) * NN) << 6);
  const u16* vtbase = vt + (size_t)((b * TT + t_kv) * HEADS + h) * 64 * VTS;
  const float* adjbase = adj + (size_t)(b * TT + ta) * NN * NN;

  // Q fragments (B-operand) + adj row bases for the 4 subtiles
  bf16x8 qf[4][2];
  const float* arB[4];
#pragma unroll
  for (int s = 0; s < 4; ++s) {
    int qr = q0 + s * 16 + qi; if (qr > NN - 1) qr = NN - 1;
    const u16* qp = qbase + (size_t)qr * 64 + g * 8;
    qf[s][0] = *(const bf16x8*)qp;
    qf[s][1] = *(const bf16x8*)(qp + 32);
    arB[s] = adjbase + (size_t)qr * NN;
  }

  const int rmap = ((qi >> 2) << 3) + (qi & 3);   // K row permutation
  const u16* kb2 = kbase + (size_t)rmap * 64 + g * 8;
  const u16* vb2 = vtbase + (size_t)qi * VTS + g * 8;

  const f32x4 z4 = {0.f, 0.f, 0.f, 0.f};
  const float LG = 1.44269504f;
  const float C8 = -11.5415603f;     // -8*log2(e)

  f32x4 acc[4][4] = {};
  float lsum[4] = {0.f, 0.f, 0.f, 0.f};

  // tile-0 prefetch
  bf16x8 kc0 = *(const bf16x8*)(kb2);
  bf16x8 kc1 = *(const bf16x8*)(kb2 + 32);
  bf16x8 kc2 = *(const bf16x8*)(kb2 + 256);
  bf16x8 kc3 = *(const bf16x8*)(kb2 + 256 + 32);
  bf16x8 vc0 = *(const bf16x8*)(vb2);
  bf16x8 vc1 = *(const bf16x8*)(vb2 + 16 * VTS);
  bf16x8 vc2 = *(const bf16x8*)(vb2 + 32 * VTS);
  bf16x8 vc3 = *(const bf16x8*)(vb2 + 48 * VTS);

  for (int kt = 0; kt < 10; ++kt) {
    const int K0 = kt * 32;
    // next-tile K/VT register prefetch
    bf16x8 kn0, kn1, kn2, kn3, vn0, vn1, vn2, vn3;
    if (kt < 9) {
      const u16* kp = kb2 + (size_t)(K0 + 32) * 64;
      kn0 = *(const bf16x8*)(kp);
      kn1 = *(const bf16x8*)(kp + 32);
      kn2 = *(const bf16x8*)(kp + 256);
      kn3 = *(const bf16x8*)(kp + 256 + 32);
      const u16* vp = vb2 + (K0 + 32);
      vn0 = *(const bf16x8*)(vp);
      vn1 = *(const bf16x8*)(vp + 16 * VTS);
      vn2 = *(const bf16x8*)(vp + 32 * VTS);
      vn3 = *(const bf16x8*)(vp + 48 * VTS);
    }
    // adj loads for this tile (per-lane, L1/L2)
    float4 fa[4], fb[4];
#pragma unroll
    for (int s = 0; s < 4; ++s) {
      const float* ap = arB[s] + K0 + g * 8;
      fa[s] = *(const float4*)(ap);
      fb[s] = *(const float4*)(ap + 4);
    }

#pragma unroll
    for (int s = 0; s < 4; ++s) {
      f32x4 s0 = MFMA(kc0, qf[s][0], z4);
      s0 = MFMA(kc1, qf[s][1], s0);
      f32x4 s1 = MFMA(kc2, qf[s][0], z4);
      s1 = MFMA(kc3, qf[s][1], s1);
      float p[8];
      float av;
      av = fa[s].x; p[0] = ex2(__builtin_fmaf(__builtin_fmaf(s0[0], av * qsc, av), LG, C8));
      av = fa[s].y; p[1] = ex2(__builtin_fmaf(__builtin_fmaf(s0[1], av * qsc, av), LG, C8));
      av = fa[s].z; p[2] = ex2(__builtin_fmaf(__builtin_fmaf(s0[2], av * qsc, av), LG, C8));
      av = fa[s].w; p[3] = ex2(__builtin_fmaf(__builtin_fmaf(s0[3], av * qsc, av), LG, C8));
      av = fb[s].x; p[4] = ex2(__builtin_fmaf(__builtin_fmaf(s1[0], av * qsc, av), LG, C8));
      av = fb[s].y; p[5] = ex2(__builtin_fmaf(__builtin_fmaf(s1[1], av * qsc, av), LG, C8));
      av = fb[s].z; p[6] = ex2(__builtin_fmaf(__builtin_fmaf(s1[2], av * qsc, av), LG, C8));
      av = fb[s].w; p[7] = ex2(__builtin_fmaf(__builtin_fmaf(s1[3], av * qsc, av), LG, C8));
      lsum[s] += ((p[0] + p[1]) + (p[2] + p[3])) + ((p[4] + p[5]) + (p[6] + p[7]));
      union { uint32_t u[4]; bf16x8 v; } pu;
      pu.u[0] = pk2(p[1], p[0]);
      pu.u[1] = pk2(p[3], p[2]);
      pu.u[2] = pk2(p[5], p[4]);
      pu.u[3] = pk2(p[7], p[6]);
      acc[s][0] = MFMA(pu.v, vc0, acc[s][0]);
      acc[s][1] = MFMA(pu.v, vc1, acc[s][1]);
      acc[s][2] = MFMA(pu.v, vc2, acc[s][2]);
      acc[s][3] = MFMA(pu.v, vc3, acc[s][3]);
    }
    kc0 = kn0; kc1 = kn1; kc2 = kn2; kc3 = kn3;
    vc0 = vn0; vc1 = vn1; vc2 = vn2; vc3 = vn3;
  }

  // ---- tail tile: keys 320..324 ----
  {
    const int T0 = 320;
    int r0 = T0 + rmap;     if (r0 > NN - 1) r0 = NN - 1;
    int r1 = T0 + rmap + 4; if (r1 > NN - 1) r1 = NN - 1;
    const u16* kp0 = kbase + (size_t)r0 * 64 + g * 8;
    const u16* kp1 = kbase + (size_t)r1 * 64 + g * 8;
    kc0 = *(const bf16x8*)kp0;  kc1 = *(const bf16x8*)(kp0 + 32);
    kc2 = *(const bf16x8*)kp1;  kc3 = *(const bf16x8*)(kp1 + 32);
    const u16* vp = vb2 + T0;                    // cols >= 325: p masked to 0 below
    vc0 = *(const bf16x8*)(vp);
    vc1 = *(const bf16x8*)(vp + 16 * VTS);
    vc2 = *(const bf16x8*)(vp + 32 * VTS);
    vc3 = *(const bf16x8*)(vp + 48 * VTS);

#pragma unroll
    for (int s = 0; s < 4; ++s) {
      f32x4 s0 = MFMA(kc0, qf[s][0], z4);
      s0 = MFMA(kc1, qf[s][1], s0);
      f32x4 s1 = MFMA(kc2, qf[s][0], z4);
      s1 = MFMA(kc3, qf[s][1], s1);
      float p[8];
#pragma unroll
      for (int j = 0; j < 4; ++j) {
        int ko = g * 8 + j;
        float av = arB[s][T0 + (ko > 4 ? 4 : ko)];
        float pv = ex2(__builtin_fmaf(__builtin_fmaf(s0[j], av * qsc, av), LG, C8));
        p[j] = (ko < 5) ? pv : 0.f;
      }
#pragma unroll
      for (int j = 0; j < 4; ++j) {
        int ko = g * 8 + 4 + j;
        float av = arB[s][T0 + (ko > 4 ? 4 : ko)];
        float pv = ex2(__builtin_fmaf(__builtin_fmaf(s1[j], av * qsc, av), LG, C8));
        p[4 + j] = (ko < 5) ? pv : 0.f;
      }
      lsum[s] += ((p[0] + p[1]) + (p[2] + p[3])) + ((p[4] + p[5]) + (p[6] + p[7]));
      union { uint32_t u[4]; bf16x8 v; } pu;
      pu.u[0] = pk2(p[1], p[0]);
      pu.u[1] = pk2(p[3], p[2]);
      pu.u[2] = pk2(p[5], p[4]);
      pu.u[3] = pk2(p[7], p[6]);
      acc[s][0] = MFMA(pu.v, vc0, acc[s][0]);
      acc[s][1] = MFMA(pu.v, vc1, acc[s][1]);
      acc[s][2] = MFMA(pu.v, vc2, acc[s][2]);
      acc[s][3] = MFMA(pu.v, vc3, acc[s][3]);
    }
  }

  // ---- epilogue: normalize + store ----
  size_t hb = ((size_t)(b * 36 + ti * TT + t) * NN) << 9;
#pragma unroll
  for (int s = 0; s < 4; ++s) {
    float v = lsum[s];
    v += __shfl_xor(v, 16);
    v += __shfl_xor(v, 32);
    float linv = 1.0f / v;
#pragma unroll
    for (int j = 0; j < 4; ++j) {
      float li = __shfl(linv, g * 4 + j);
      int qrow = q0 + s * 16 + 4 * g + j;
      if (qrow < NN) {
        u16* op = hcat + hb + ((size_t)qrow << 9) + h * 64 + qi;
#pragma unroll
        for (int dt = 0; dt < 4; ++dt)
          op[dt * 16] = f2bf(acc[s][dt][j] * li);
      }
    }
  }
}

// ---------------- temporal mix + residual + LayerNorm ----------------
__global__ __launch_bounds__(256) void mix_ln(
    const u16* __restrict__ hcat,
    const float* __restrict__ Wd,   // [12][36]
    const float* __restrict__ bd,   // [12]
    const float* __restrict__ x,
    const float* __restrict__ gamma,
    const float* __restrict__ beta,
    float* __restrict__ out)
{
  __shared__ float sH[36 * 512];
  __shared__ float sWd[12 * 36];
  __shared__ float sred[8];
  int bn = blockIdx.x;
  int b = bn / NN, n = bn - b * NN;
  int tid = threadIdx.x;
  int lane = tid & 63, wid = tid >> 6;

  for (int i = tid; i < 12 * 36; i += 256) sWd[i] = Wd[i];
  for (int i = tid; i < 36 * 512; i += 256) {
    int w = i >> 9, d = i & 511;
    sH[i] = bf2f(hcat[(((size_t)(b * 36 + w) * NN + n) << 9) + d]);
  }
  __syncthreads();

  for (int t = 0; t < TT; ++t) {
    float a0 = 0.f, a1 = 0.f;
#pragma unroll
    for (int w = 0; w < 36; ++w) {
      float wv = sWd[t * 36 + w];
      a0 += sH[(w << 9) + tid] * wv;
      a1 += sH[(w << 9) + 256 + tid] * wv;
    }
    size_t xoff = ((size_t)(b * TT + t) * NN + n) << 9;
    float bdt = bd[t];
    float y0 = a0 + bdt + x[xoff + tid];
    float y1 = a1 + bdt + x[xoff + 256 + tid];
    float s = y0 + y1, ss = y0 * y0 + y1 * y1;
#pragma unroll
    for (int off = 32; off > 0; off >>= 1) {
      s += __shfl_down(s, off);
      ss += __shfl_down(ss, off);
    }
    if (lane == 0) { sred[wid * 2] = s; sred[wid * 2 + 1] = ss; }
    __syncthreads();
    float stot = sred[0] + sred[2] + sred[4] + sred[6];
    float sstot = sred[1] + sred[3] + sred[5] + sred[7];
    float mu = stot * (1.0f / 512.0f);
    float var = sstot * (1.0f / 512.0f) - mu * mu;
    float rstd = rsqrtf(var + 1e-5f);
    out[xoff + tid] = (y0 - mu) * rstd * gamma[tid] + beta[tid];
    out[xoff + 256 + tid] = (y1 - mu) * rstd * gamma[tid + 256] + beta[tid + 256];
    __syncthreads();
  }
}

extern "C" void kernel_launch(void* const* d_in, const int* in_sizes, int n_in,
                              void* d_out, int out_size, void* d_ws, size_t ws_size,
                              hipStream_t stream) {
  const float* x     = (const float*)d_in[0];
  const float* adj   = (const float*)d_in[1];
  // d_in[2] = s_adj: unused by the reference
  const float* Wq    = (const float*)d_in[3];
  const float* bq    = (const float*)d_in[4];
  const float* Wk    = (const float*)d_in[5];
  const float* bk    = (const float*)d_in[6];
  const float* Wv    = (const float*)d_in[7];
  const float* bv    = (const float*)d_in[8];
  const float* Wd    = (const float*)d_in[9];
  const float* bd    = (const float*)d_in[10];
  const float* gamma = (const float*)d_in[11];
  const float* beta  = (const float*)d_in[12];
  float* out = (float*)d_out;

  char* ws = (char*)d_ws;
  size_t off = 0;
  auto alloc = [&](size_t bytes) {
    void* p = ws + off;
    off += (bytes + 255) & ~(size_t)255;
    return p;
  };
  u16* Wb     = (u16*)alloc(1536 * 512 * 2);         // [Wq;Wk;Wv] bf16
  float* bias = (float*)alloc(1536 * 4);             // [bq;bk;bv]
  u16* qkv    = (u16*)alloc(2 * QKV_ELE * 2);        // q,k bf16 (B,T,H,N,64)
  u16* hcat   = (u16*)alloc(3 * QKV_ELE * 2);        // (B,36,N,512) bf16
  u16* vtb    = (u16*)alloc((size_t)BB * TT * HEADS * 64 * VTS * 2);  // V^T padded

  pack_w<<<dim3(768), dim3(256), 0, stream>>>(Wq, Wk, Wv, bq, bk, bv, Wb, bias);
  proj_gemm<<<dim3((MROWS + 127) / 128, 1536 / 128), dim3(256), 0, stream>>>(x, Wb, bias, qkv, vtb);
  attn<<<dim3(BB * TT * WIN * 6 * 2), dim3(256), 0, stream>>>(qkv, vtb, adj, hcat);
  mix_ln<<<dim3(BB * NN), dim3(256), 0, stream>>>(hcat, Wd, bd, x, gamma, beta, out);
}